// Round 7
// baseline (150.105 us; speedup 1.0000x reference)
//
#include <hip/hip_runtime.h>
#include <stdint.h>

typedef uint32_t u32;
typedef uint64_t u64;

#define NB 4
#define NA 9
#define NH 34
#define NW 60
#define HW (NH*NW)            // 2040
#define NBOX (NA*HW)          // 18360
#define PRE_NMS 3000
#define POST_NMS 300
#define NBUCKET 4096
#define SEGCAP 4096
#define NTH 1024
#define PER 18                // 18*1024 = 18432 >= 18360
#define CORNER 512            // examined-candidate corner (fallback covers rest)
#define CW 8                  // words per corner row (512/64)
#define SUB 16                // candidates per serial sub-chunk
#define NCH (CORNER/SUB)      // 32 sub-chunks

// Anchor widths/heights (f64->f32 roundings, matching np.array(..., float32)).
__device__ __constant__ float c_aw[9] = {
  45.254833995939045f, 64.0f,  90.50966799187808f,
  90.50966799187808f,  128.0f, 181.01933598375617f,
  181.01933598375617f, 256.0f, 362.03867196751233f };
__device__ __constant__ float c_ah[9] = {
  90.50966799187808f,  64.0f,  45.254833995939045f,
  181.01933598375617f, 128.0f, 90.50966799187808f,
  362.03867196751233f, 256.0f, 181.01933598375617f };

__device__ __forceinline__ u64 readlane64(u64 v, int lane) {
  u32 lo = __builtin_amdgcn_readlane((u32)(v & 0xffffffffull), lane);
  u32 hi = __builtin_amdgcn_readlane((u32)(v >> 32), lane);
  return ((u64)hi << 32) | lo;
}

__device__ __forceinline__ float4 decode_box(const float* __restrict__ dl, int idx) {
  int a = idx / HW;
  int r = idx - a * HW;
  int h = r / NW;
  int w = r - h * NW;
  const float* dp = dl + (4 * a) * HW + r;
  float tx = dp[0];
  float ty = dp[HW];
  float tw = dp[2 * HW];
  float th = dp[3 * HW];
  float aw = c_aw[a], ah = c_ah[a];
  float ctr_x = ((float)w + 0.5f) * 16.0f + tx * aw;
  float ctr_y = ((float)h + 0.5f) * 16.0f + ty * ah;
  float w1 = expf(tw) * aw;
  float h1 = expf(th) * ah;
  float x1 = ctr_x - 0.5f * w1;
  float y1 = ctr_y - 0.5f * h1;
  float x2 = x1 + w1;
  float y2 = y1 + h1;
  x1 = fminf(fmaxf(x1, 0.0f), 959.0f);
  x2 = fminf(fmaxf(x2, 0.0f), 959.0f);
  y1 = fminf(fmaxf(y1, 0.0f), 543.0f);
  y2 = fminf(fmaxf(y2, 0.0f), 543.0f);
  return make_float4(x1, y1, x2, y2);
}

// ---------------------------------------------------------------------------
// K1: sort-free exact ranking (verified rounds 4-6, unchanged).
// ---------------------------------------------------------------------------
__global__ void __launch_bounds__(NTH)
topk_rank_decode_kernel(const float* __restrict__ scores,
                        const float* __restrict__ deltas,
                        float4* __restrict__ boxes_ws)
{
  __shared__ u32 s_base[NBUCKET];
  __shared__ u32 s_cnt[NBUCKET];
  __shared__ u64 s_keys[SEGCAP];
  __shared__ u32 s_sfx[NTH];

  const int tid = threadIdx.x;
  const int b   = blockIdx.x;
  const float* sc = scores + b * NBOX;

  for (int t = tid; t < NBUCKET; t += NTH) s_cnt[t] = 0;
  __syncthreads();

  for (int m = 0; m < PER; ++m) {
    int i = tid + m * NTH;
    if (i < NBOX) {
      float s = sc[i];
      int bk = (int)(s * (float)NBUCKET);
      bk = bk < 0 ? 0 : (bk > NBUCKET - 1 ? NBUCKET - 1 : bk);
      atomicAdd(&s_cnt[bk], 1u);
    }
  }
  __syncthreads();

  u32 h0 = s_cnt[4*tid], h1 = s_cnt[4*tid+1], h2 = s_cnt[4*tid+2], h3 = s_cnt[4*tid+3];
  s_sfx[tid] = h0 + h1 + h2 + h3;
  __syncthreads();
  for (int d = 1; d < NTH; d <<= 1) {
    u32 v = (tid + d < NTH) ? s_sfx[tid + d] : 0u;
    __syncthreads();
    s_sfx[tid] += v;
    __syncthreads();
  }

  {
    u32 Gn = (tid < NTH - 1) ? s_sfx[tid + 1] : 0u;
    s_base[4*tid+3] = Gn;
    s_base[4*tid+2] = Gn + h3;
    s_base[4*tid+1] = Gn + h3 + h2;
    s_base[4*tid+0] = Gn + h3 + h2 + h1;
  }
  __syncthreads();

  for (int t = tid; t < NBUCKET; t += NTH) s_cnt[t] = 0;
  for (int t = tid; t < SEGCAP; t += NTH) s_keys[t] = 0ull;
  __syncthreads();

  for (int m = 0; m < PER; ++m) {
    int i = tid + m * NTH;
    if (i < NBOX) {
      float s = sc[i];
      int bk = (int)(s * (float)NBUCKET);
      bk = bk < 0 ? 0 : (bk > NBUCKET - 1 ? NBUCKET - 1 : bk);
      u32 base = s_base[bk];
      if (base < PRE_NMS) {
        u32 loc = atomicAdd(&s_cnt[bk], 1u);
        u32 pos = base + loc;
        if (pos < SEGCAP) {
          u64 key = ((u64)__float_as_uint(s) << 32) | (u32)(~(u32)i);
          s_keys[pos] = key;
        }
      }
    }
  }
  __syncthreads();

  const float* dl = deltas + b * (4 * NA * HW);
  for (int m = 0; m < SEGCAP / NTH; ++m) {
    int p = tid + m * NTH;
    u64 key = s_keys[p];
    float s = __uint_as_float((u32)(key >> 32));
    int bk = (int)(s * (float)NBUCKET);
    bk = bk < 0 ? 0 : (bk > NBUCKET - 1 ? NBUCKET - 1 : bk);
    u32 base = s_base[bk];
    u32 cnt  = s_cnt[bk];
    u32 local = 0;
    for (u32 q = base; q < base + cnt; ++q)
      local += (s_keys[q] > key) ? 1u : 0u;
    u32 R = base + local;
    if (key != 0ull && R < PRE_NMS) {
      int idx = (int)(~(u32)key);
      boxes_ws[b * PRE_NMS + R] = decode_box(dl, idx);
    }
  }
}

// ---------------------------------------------------------------------------
// K2: 512x512 suppression corner only (verified round 6, unchanged).
// ---------------------------------------------------------------------------
__global__ void __launch_bounds__(256)
mask_corner_kernel(const float4* __restrict__ boxes_ws, u64* __restrict__ masks2)
{
  const int wq = blockIdx.x;          // word pair: words 2wq, 2wq+1
  const int rh = blockIdx.y;          // row half
  const int b  = blockIdx.z;
  const int tid = threadIdx.x;
  __shared__ float4 s_cb[128];
  __shared__ float  s_ca[128];
  if (tid < 128) {
    int j = 128 * wq + tid;
    float4 v = boxes_ws[b * PRE_NMS + j];
    s_cb[tid] = v;
    s_ca[tid] = (v.z - v.x) * (v.w - v.y);
  }
  __syncthreads();
  int row = rh * 256 + tid;
  float4 r = boxes_ws[b * PRE_NMS + row];
  float ra = (r.z - r.x) * (r.w - r.y);
  #pragma unroll
  for (int wl = 0; wl < 2; ++wl) {
    u64 word = 0;
    #pragma unroll
    for (int k = 0; k < 64; ++k) {
      float4 cb = s_cb[wl * 64 + k];
      float iw = fminf(r.z, cb.z) - fmaxf(r.x, cb.x);
      float ih = fminf(r.w, cb.w) - fmaxf(r.y, cb.y);
      iw = fmaxf(iw, 0.0f);
      ih = fmaxf(ih, 0.0f);
      float inter = iw * ih;
      float uni = ra + s_ca[wl * 64 + k] - inter;
      word |= ((u64)(inter > 0.7f * fmaxf(uni, 1e-8f))) << k;
    }
    masks2[((size_t)b * CORNER + row) * CW + (2 * wq + wl)] = word;
  }
}

// ---------------------------------------------------------------------------
// K3 v6: array-free LDS-corner greedy reduce.
// Per-lane serial state is exactly TWO u64 scalars (removed, D) — nothing the
// compiler can demote to scratch (rounds 4-6 showed 16-element u64 local
// arrays always go to scratch here; VGPR_Count 68/56 < array size was the
// smoking gun). Per 16-candidate chunk: 1 prefetched diagonal-word ds_read,
// 1 readlane of the removed word, a short SALU keep chain, then 16
// UNCONDITIONAL batched ds_read_b64 of row words + conditional ORs.
// Exact greedy; in-kernel fallback continues past candidate 512 if needed.
// ---------------------------------------------------------------------------
__global__ void __launch_bounds__(256)
nms_reduce_kernel(const float4* __restrict__ boxes_ws,
                  const u64* __restrict__ masks2,
                  float* __restrict__ out)
{
  const int b = blockIdx.x;
  const int tid = threadIdx.x;
  __shared__ __align__(16) u64 s_corner[CORNER * CW];   // 32 KB
  __shared__ u32 s_kept[POST_NMS];
  __shared__ u32 s_nk;

  // ---- phase A: corner -> LDS (coalesced, 256 threads) ----
  {
    const ulonglong2* src = (const ulonglong2*)(masks2 + (size_t)b * CORNER * CW);
    ulonglong2* dst = (ulonglong2*)s_corner;
    #pragma unroll
    for (int k = 0; k < (CORNER * CW / 2) / 256; ++k)
      dst[tid + k * 256] = src[tid + k * 256];
  }
  __syncthreads();

  // ---- phase B: wave-0 serial greedy over corner (scalar state only) ----
  if (tid < 64) {
    const int lane = tid;
    const int wl8 = lane & 7;           // row-word this lane reads in OR phase
    u64 removed = 0ull;                 // lanes 0-7 meaningful (512 bits)
    int nk = 0;
    bool done = false;

    // diagonal word for chunk 0: lane k<16 = word 0 of row k
    u64 D = (lane < 16) ? s_corner[lane * CW + 0] : 0ull;

    for (int j = 0; j < NCH && !done; ++j) {
      const int base = j * SUB;
      const int w0 = j >> 2;            // removed-word holding these 16 bits
      const int sh = (j & 3) * 16;
      // prefetch next chunk's diagonal word (independent of this chunk)
      const int jn = j + 1;
      u64 Dn = (jn < NCH && lane < 16)
                 ? s_corner[(jn * SUB + lane) * CW + (jn >> 2)] : 0ull;
      // validate 16 candidates vs accumulated removed bitmap
      u64 remw = readlane64(removed, w0);
      u32 a = (u32)((~remw >> sh) & 0xFFFFull);
      // uniform keep chain (SALU + readlane of D only)
      u64 supw = 0ull;
      u32 keepm = 0;
      while (a) {
        int k = __ffs(a) - 1;
        a &= a - 1u;
        if (!((supw >> (sh + k)) & 1ull)) {
          keepm |= 1u << k;
          if (lane == 0) s_kept[nk] = (u32)(base + k);
          ++nk;
          if (nk >= POST_NMS) { done = true; break; }
          supw |= readlane64(D, k);
        }
      }
      // OR kept rows straight from LDS: 16 unconditional batched loads,
      // conditional merge. No staging arrays.
      if (!done) {
        #pragma unroll
        for (int k = 0; k < SUB; ++k) {
          u64 rw = s_corner[(base + k) * CW + wl8];
          if ((keepm >> k) & 1u) removed |= rw;
        }
      }
      D = Dn;
    }

    // ---- phase C: exact fallback past candidate 512 (not taken on this
    // data; correctness net). Round-1-verified register-NMS logic. ----
    if (nk < POST_NMS) {
      float4 kb[5];
      float  ka[5];
      #pragma unroll
      for (int s = 0; s < 5; ++s) {
        int t = s * 64 + lane;
        float4 v = make_float4(0.f, 0.f, 0.f, 0.f);
        if (t < nk) v = boxes_ws[b * PRE_NMS + s_kept[t]];
        kb[s] = v;
        ka[s] = (v.z - v.x) * (v.w - v.y);
      }
      for (int i = CORNER; i < PRE_NMS; ++i) {
        if (nk >= POST_NMS) break;
        float4 c = boxes_ws[b * PRE_NMS + i];
        float carea = (c.z - c.x) * (c.w - c.y);
        bool over = false;
        #pragma unroll
        for (int s = 0; s < 5; ++s) {
          if (s * 64 < nk) {
            if (s * 64 + lane < nk) {
              float iw = fminf(kb[s].z, c.z) - fmaxf(kb[s].x, c.x);
              float ih = fminf(kb[s].w, c.w) - fmaxf(kb[s].y, c.y);
              iw = fmaxf(iw, 0.0f);
              ih = fmaxf(ih, 0.0f);
              float inter = iw * ih;
              float uni = ka[s] + carea - inter;
              over = over || (inter > 0.7f * fmaxf(uni, 1e-8f));
            }
          }
        }
        if (__ballot((int)over) == 0ull) {
          int s = nk >> 6, l = nk & 63;
          #pragma unroll
          for (int q = 0; q < 5; ++q)
            if (q == s && lane == l) { kb[q] = c; ka[q] = carea; }
          if (lane == 0) s_kept[nk] = (u32)i;
          ++nk;
        }
      }
    }
    if (lane == 0) s_nk = (u32)nk;
  }
  __syncthreads();

  // ---- emit: first nk kept (score order), zero-pad to 300 ----
  u32 fnk = s_nk;
  float4* outv = (float4*)out;
  for (int t = tid; t < POST_NMS; t += 256) {
    float4 v = make_float4(0.f, 0.f, 0.f, 0.f);
    if ((u32)t < fnk) v = boxes_ws[b * PRE_NMS + s_kept[t]];
    outv[b * POST_NMS + t] = v;
  }
}

// ---------------------------------------------------------------------------
// Fallback: round-1 monolithic kernel (verified) if ws is too small.
// ---------------------------------------------------------------------------
__global__ void __launch_bounds__(NTH)
rpn_proposal_mono(const float* __restrict__ scores,
                  const float* __restrict__ deltas,
                  float* __restrict__ out)
{
  __shared__ __align__(16) char smem[16384 + 32768 + 4096];
  u32* s_hist = (u32*)smem;
  u64* s_cand = (u64*)(smem + 16384);
  u32* s_sfx  = (u32*)(smem + 16384 + 32768);
  float4* s_box = (float4*)smem;
  __shared__ u32 s_kept[POST_NMS];
  __shared__ u32 s_meta[4];

  const int tid = threadIdx.x;
  const int b   = blockIdx.x;
  const float* sc = scores + b * NBOX;

  for (int t = tid; t < NBUCKET; t += NTH) s_hist[t] = 0;
  if (tid < 4) s_meta[tid] = 0;
  __syncthreads();
  for (int m = 0; m < PER; ++m) {
    int i = tid + m * NTH;
    if (i < NBOX) {
      float s = sc[i];
      int bk = (int)(s * (float)NBUCKET);
      bk = bk < 0 ? 0 : (bk > NBUCKET - 1 ? NBUCKET - 1 : bk);
      atomicAdd(&s_hist[bk], 1u);
    }
  }
  __syncthreads();
  {
    u32 g = s_hist[4*tid] + s_hist[4*tid+1] + s_hist[4*tid+2] + s_hist[4*tid+3];
    s_sfx[tid] = g;
  }
  __syncthreads();
  for (int d = 1; d < NTH; d <<= 1) {
    u32 v = (tid + d < NTH) ? s_sfx[tid + d] : 0u;
    __syncthreads();
    s_sfx[tid] += v;
    __syncthreads();
  }
  {
    u32 sg  = s_sfx[tid];
    u32 sgn = (tid < NTH - 1) ? s_sfx[tid + 1] : 0u;
    if (sg >= PRE_NMS && sgn < PRE_NMS) {
      u32 c = sgn;
      for (int t = 4 * tid + 3; t >= 4 * tid; --t) {
        c += s_hist[t];
        if (c >= PRE_NMS) { s_meta[0] = (u32)t; s_meta[1] = c; break; }
      }
    }
  }
  __syncthreads();
  const u32 T = s_meta[0];
  for (int m = 0; m < PER; ++m) {
    int i = tid + m * NTH;
    if (i < NBOX) {
      float s = sc[i];
      int bk = (int)(s * (float)NBUCKET);
      bk = bk < 0 ? 0 : (bk > NBUCKET - 1 ? NBUCKET - 1 : bk);
      if ((u32)bk >= T) {
        u32 pos = atomicAdd(&s_meta[2], 1u);
        if (pos < SEGCAP) {
          u64 key = ((u64)__float_as_uint(s) << 32) | (u32)(~(u32)i);
          s_cand[pos] = key;
        }
      }
    }
  }
  __syncthreads();
  {
    u32 C = s_meta[2]; if (C > SEGCAP) C = SEGCAP;
    for (u32 p = C + tid; p < SEGCAP; p += NTH) s_cand[p] = 0ull;
  }
  for (int kk = 2; kk <= SEGCAP; kk <<= 1) {
    for (int j = kk >> 1; j > 0; j >>= 1) {
      __syncthreads();
      #pragma unroll
      for (int m = 0; m < 2; ++m) {
        int t = tid + m * NTH;
        int i = ((t & ~(j - 1)) << 1) | (t & (j - 1));
        int p = i | j;
        u64 a  = s_cand[i];
        u64 bb = s_cand[p];
        bool desc = (i & kk) == 0;
        bool sw = desc ? (a < bb) : (a > bb);
        if (sw) { s_cand[i] = bb; s_cand[p] = a; }
      }
    }
  }
  __syncthreads();
  const float* dl = deltas + b * (4 * NA * HW);
  float4 bx[3];
  #pragma unroll
  for (int m = 0; m < 3; ++m) {
    int k = tid + m * NTH;
    if (k < PRE_NMS) {
      u64 key = s_cand[k];
      bx[m] = decode_box(dl, (int)(~(u32)key));
    }
  }
  __syncthreads();
  #pragma unroll
  for (int m = 0; m < 3; ++m) {
    int k = tid + m * NTH;
    if (k < PRE_NMS) s_box[k] = bx[m];
  }
  __syncthreads();
  if (tid < 64) {
    const int lane = tid;
    float4 kb[5];
    float  ka[5];
    int nk = 0;
    for (int i = 0; i < PRE_NMS; ++i) {
      if (nk >= POST_NMS) break;
      float4 c = s_box[i];
      float carea = (c.z - c.x) * (c.w - c.y);
      bool over = false;
      #pragma unroll
      for (int s = 0; s < 5; ++s) {
        if (s * 64 < nk) {
          if (s * 64 + lane < nk) {
            float iw = fminf(kb[s].z, c.z) - fmaxf(kb[s].x, c.x);
            float ih = fminf(kb[s].w, c.w) - fmaxf(kb[s].y, c.y);
            iw = fmaxf(iw, 0.0f);
            ih = fmaxf(ih, 0.0f);
            float inter = iw * ih;
            float uni = ka[s] + carea - inter;
            over = over || (inter > 0.7f * fmaxf(uni, 1e-8f));
          }
        }
      }
      if (__ballot((int)over) == 0ull) {
        int s = nk >> 6, l = nk & 63;
        #pragma unroll
        for (int q = 0; q < 5; ++q)
          if (q == s && lane == l) { kb[q] = c; ka[q] = carea; }
        if (lane == 0) s_kept[nk] = (u32)i;
        ++nk;
      }
    }
    if (lane == 0) s_meta[3] = (u32)nk;
  }
  __syncthreads();
  if (tid < POST_NMS) {
    u32 nk = s_meta[3];
    float4 v = make_float4(0.0f, 0.0f, 0.0f, 0.0f);
    if ((u32)tid < nk) v = s_box[s_kept[tid]];
    ((float4*)out)[b * POST_NMS + tid] = v;
  }
}

extern "C" void kernel_launch(void* const* d_in, const int* in_sizes, int n_in,
                              void* d_out, int out_size, void* d_ws, size_t ws_size,
                              hipStream_t stream) {
  const float* scores = (const float*)d_in[0];
  const float* deltas = (const float*)d_in[1];
  (void)in_sizes; (void)n_in; (void)out_size;

  const size_t mask_off   = 196608;                                   // 192KB aligned
  const size_t mask_bytes = (size_t)NB * CORNER * CW * sizeof(u64);   // 128 KB
  const size_t need       = mask_off + mask_bytes;

  if (ws_size >= need) {
    float4* boxes_ws = (float4*)d_ws;
    u64*    masks2   = (u64*)((char*)d_ws + mask_off);
    topk_rank_decode_kernel<<<dim3(NB), dim3(NTH), 0, stream>>>(scores, deltas, boxes_ws);
    mask_corner_kernel<<<dim3(4, 2, NB), dim3(256), 0, stream>>>(boxes_ws, masks2);
    nms_reduce_kernel<<<dim3(NB), dim3(256), 0, stream>>>(boxes_ws, masks2, (float*)d_out);
  } else {
    rpn_proposal_mono<<<dim3(NB), dim3(NTH), 0, stream>>>(scores, deltas, (float*)d_out);
  }
}

// Round 8
// 143.542 us; speedup vs baseline: 1.0457x; 1.0457x over previous
//
#include <hip/hip_runtime.h>
#include <stdint.h>

typedef uint32_t u32;
typedef uint64_t u64;

#define NB 4
#define NA 9
#define NH 34
#define NW 60
#define HW (NH*NW)            // 2040
#define NBOX (NA*HW)          // 18360
#define PRE_NMS 3000
#define POST_NMS 300
#define NBUCKET 4096
#define SEGCAP 4096
#define NTH 1024
#define PER 18                // 18*1024 = 18432 >= 18360
#define NCAND 1536            // bit-matrix coverage (examined ~1160 measured)
#define MW 24                 // words per mask row (1536/64)
#define NCHK 24               // 64-candidate chunks

// Anchor widths/heights (f64->f32 roundings, matching np.array(..., float32)).
__device__ __constant__ float c_aw[9] = {
  45.254833995939045f, 64.0f,  90.50966799187808f,
  90.50966799187808f,  128.0f, 181.01933598375617f,
  181.01933598375617f, 256.0f, 362.03867196751233f };
__device__ __constant__ float c_ah[9] = {
  90.50966799187808f,  64.0f,  45.254833995939045f,
  181.01933598375617f, 128.0f, 90.50966799187808f,
  362.03867196751233f, 256.0f, 181.01933598375617f };

__device__ __forceinline__ u64 readlane64(u64 v, int lane) {
  u32 lo = __builtin_amdgcn_readlane((u32)(v & 0xffffffffull), lane);
  u32 hi = __builtin_amdgcn_readlane((u32)(v >> 32), lane);
  return ((u64)hi << 32) | lo;
}

__device__ __forceinline__ float4 decode_box(const float* __restrict__ dl, int idx) {
  int a = idx / HW;
  int r = idx - a * HW;
  int h = r / NW;
  int w = r - h * NW;
  const float* dp = dl + (4 * a) * HW + r;
  float tx = dp[0];
  float ty = dp[HW];
  float tw = dp[2 * HW];
  float th = dp[3 * HW];
  float aw = c_aw[a], ah = c_ah[a];
  float ctr_x = ((float)w + 0.5f) * 16.0f + tx * aw;
  float ctr_y = ((float)h + 0.5f) * 16.0f + ty * ah;
  float w1 = expf(tw) * aw;
  float h1 = expf(th) * ah;
  float x1 = ctr_x - 0.5f * w1;
  float y1 = ctr_y - 0.5f * h1;
  float x2 = x1 + w1;
  float y2 = y1 + h1;
  x1 = fminf(fmaxf(x1, 0.0f), 959.0f);
  x2 = fminf(fmaxf(x2, 0.0f), 959.0f);
  y1 = fminf(fmaxf(y1, 0.0f), 543.0f);
  y2 = fminf(fmaxf(y2, 0.0f), 543.0f);
  return make_float4(x1, y1, x2, y2);
}

// ---------------------------------------------------------------------------
// K1: sort-free exact ranking (verified rounds 4-7, unchanged).
// ---------------------------------------------------------------------------
__global__ void __launch_bounds__(NTH)
topk_rank_decode_kernel(const float* __restrict__ scores,
                        const float* __restrict__ deltas,
                        float4* __restrict__ boxes_ws)
{
  __shared__ u32 s_base[NBUCKET];
  __shared__ u32 s_cnt[NBUCKET];
  __shared__ u64 s_keys[SEGCAP];
  __shared__ u32 s_sfx[NTH];

  const int tid = threadIdx.x;
  const int b   = blockIdx.x;
  const float* sc = scores + b * NBOX;

  for (int t = tid; t < NBUCKET; t += NTH) s_cnt[t] = 0;
  __syncthreads();

  for (int m = 0; m < PER; ++m) {
    int i = tid + m * NTH;
    if (i < NBOX) {
      float s = sc[i];
      int bk = (int)(s * (float)NBUCKET);
      bk = bk < 0 ? 0 : (bk > NBUCKET - 1 ? NBUCKET - 1 : bk);
      atomicAdd(&s_cnt[bk], 1u);
    }
  }
  __syncthreads();

  u32 h0 = s_cnt[4*tid], h1 = s_cnt[4*tid+1], h2 = s_cnt[4*tid+2], h3 = s_cnt[4*tid+3];
  s_sfx[tid] = h0 + h1 + h2 + h3;
  __syncthreads();
  for (int d = 1; d < NTH; d <<= 1) {
    u32 v = (tid + d < NTH) ? s_sfx[tid + d] : 0u;
    __syncthreads();
    s_sfx[tid] += v;
    __syncthreads();
  }

  {
    u32 Gn = (tid < NTH - 1) ? s_sfx[tid + 1] : 0u;
    s_base[4*tid+3] = Gn;
    s_base[4*tid+2] = Gn + h3;
    s_base[4*tid+1] = Gn + h3 + h2;
    s_base[4*tid+0] = Gn + h3 + h2 + h1;
  }
  __syncthreads();

  for (int t = tid; t < NBUCKET; t += NTH) s_cnt[t] = 0;
  for (int t = tid; t < SEGCAP; t += NTH) s_keys[t] = 0ull;
  __syncthreads();

  for (int m = 0; m < PER; ++m) {
    int i = tid + m * NTH;
    if (i < NBOX) {
      float s = sc[i];
      int bk = (int)(s * (float)NBUCKET);
      bk = bk < 0 ? 0 : (bk > NBUCKET - 1 ? NBUCKET - 1 : bk);
      u32 base = s_base[bk];
      if (base < PRE_NMS) {
        u32 loc = atomicAdd(&s_cnt[bk], 1u);
        u32 pos = base + loc;
        if (pos < SEGCAP) {
          u64 key = ((u64)__float_as_uint(s) << 32) | (u32)(~(u32)i);
          s_keys[pos] = key;
        }
      }
    }
  }
  __syncthreads();

  const float* dl = deltas + b * (4 * NA * HW);
  for (int m = 0; m < SEGCAP / NTH; ++m) {
    int p = tid + m * NTH;
    u64 key = s_keys[p];
    float s = __uint_as_float((u32)(key >> 32));
    int bk = (int)(s * (float)NBUCKET);
    bk = bk < 0 ? 0 : (bk > NBUCKET - 1 ? NBUCKET - 1 : bk);
    u32 base = s_base[bk];
    u32 cnt  = s_cnt[bk];
    u32 local = 0;
    for (u32 q = base; q < base + cnt; ++q)
      local += (s_keys[q] > key) ? 1u : 0u;
    u32 R = base + local;
    if (key != 0ull && R < PRE_NMS) {
      int idx = (int)(~(u32)key);
      boxes_ws[b * PRE_NMS + R] = decode_box(dl, idx);
    }
  }
}

// ---------------------------------------------------------------------------
// K2 v3: 1536x1536 suppression matrix. masks2[b][row][w], w<24.
// grid (24 words, 6 row-blocks, NB) x 256 threads; 64 IoU/thread.
// ---------------------------------------------------------------------------
__global__ void __launch_bounds__(256)
mask_corner_kernel(const float4* __restrict__ boxes_ws, u64* __restrict__ masks2)
{
  const int wq = blockIdx.x;          // word 0..23
  const int rb = blockIdx.y;          // row block 0..5
  const int b  = blockIdx.z;
  const int tid = threadIdx.x;
  __shared__ float4 s_cb[64];
  __shared__ float  s_ca[64];
  if (tid < 64) {
    int j = wq * 64 + tid;            // < 1536 < PRE_NMS
    float4 v = boxes_ws[b * PRE_NMS + j];
    s_cb[tid] = v;
    s_ca[tid] = (v.z - v.x) * (v.w - v.y);
  }
  __syncthreads();
  int row = rb * 256 + tid;           // < 1536
  float4 r = boxes_ws[b * PRE_NMS + row];
  float ra = (r.z - r.x) * (r.w - r.y);
  u64 word = 0;
  #pragma unroll
  for (int k = 0; k < 64; ++k) {
    float4 cb = s_cb[k];
    float iw = fminf(r.z, cb.z) - fmaxf(r.x, cb.x);
    float ih = fminf(r.w, cb.w) - fmaxf(r.y, cb.y);
    iw = fmaxf(iw, 0.0f);
    ih = fmaxf(ih, 0.0f);
    float inter = iw * ih;
    float uni = ra + s_ca[k] - inter;
    word |= ((u64)(inter > 0.7f * fmaxf(uni, 1e-8f))) << k;
  }
  masks2[((size_t)b * NCAND + row) * MW + wq] = word;
}

// ---------------------------------------------------------------------------
// K3 v8: kept-bitmap greedy reduce, 64-candidate chunks, zero local arrays.
// Lane m owns the ROW of candidate chunk*64+m (24 words = 12 named ulonglong2
// registers, contiguous coalesced loads, prefetched one chunk ahead into a
// second named set). keptmap (1536 bits) is replicated in 12 named registers
// per lane; update per chunk is one wave-uniform OR into a STATIC word.
// Cross-chunk suppression: s = row & keptmap, avail = ballot(s==0) -- one
// u64. Intra-chunk: SALU chain + readlane of the chunk's diagonal word
// (static component of the row registers). Fully unrolled 24-chunk sequence
// => every index static => nothing for the compiler to demote to scratch
// (rounds 4-7: local u64 arrays always went to scratch; phase C fallback
// dominated at 46us because keep rate is ~26%, examined ~1160 > CORNER 512).
// Exact greedy; phase C fallback covers candidates >= 1536 (not taken here).
// ---------------------------------------------------------------------------
__global__ void __launch_bounds__(64)
nms_reduce_kernel(const float4* __restrict__ boxes_ws,
                  const u64* __restrict__ masks2,
                  float* __restrict__ out)
{
  const int b = blockIdx.x;
  const int lane = threadIdx.x;
  __shared__ u32 s_kept[POST_NMS];

  const u64* mrow = masks2 + (size_t)b * NCAND * MW;
  int nk = 0;
  bool done = false;

  ulonglong2 cur0, cur1, cur2, cur3, cur4, cur5, cur6, cur7, cur8, cur9, cur10, cur11;
  ulonglong2 nxt0, nxt1, nxt2, nxt3, nxt4, nxt5, nxt6, nxt7, nxt8, nxt9, nxt10, nxt11;
  ulonglong2 km0, km1, km2, km3, km4, km5, km6, km7, km8, km9, km10, km11;
  km0 = km1 = km2 = km3 = km4 = km5 = km6 = km7 = km8 = km9 = km10 = km11
      = make_ulonglong2(0ull, 0ull);

#define LOADCUR(C) { const ulonglong2* p_ = (const ulonglong2*)mrow + ((size_t)((C)*64 + lane)) * (MW/2); \
  cur0=p_[0]; cur1=p_[1]; cur2=p_[2]; cur3=p_[3]; cur4=p_[4]; cur5=p_[5]; \
  cur6=p_[6]; cur7=p_[7]; cur8=p_[8]; cur9=p_[9]; cur10=p_[10]; cur11=p_[11]; }
#define PREF(C) { const ulonglong2* p_ = (const ulonglong2*)mrow + ((size_t)((C)*64 + lane)) * (MW/2); \
  nxt0=p_[0]; nxt1=p_[1]; nxt2=p_[2]; nxt3=p_[3]; nxt4=p_[4]; nxt5=p_[5]; \
  nxt6=p_[6]; nxt7=p_[7]; nxt8=p_[8]; nxt9=p_[9]; nxt10=p_[10]; nxt11=p_[11]; }
#define ROLL { cur0=nxt0; cur1=nxt1; cur2=nxt2; cur3=nxt3; cur4=nxt4; cur5=nxt5; \
  cur6=nxt6; cur7=nxt7; cur8=nxt8; cur9=nxt9; cur10=nxt10; cur11=nxt11; }
#define DO_CHUNK(C, DW, KM) {                                            \
    u64 sA_ = (cur0.x & km0.x) | (cur0.y & km0.y)                        \
            | (cur1.x & km1.x) | (cur1.y & km1.y)                        \
            | (cur2.x & km2.x) | (cur2.y & km2.y)                        \
            | (cur3.x & km3.x) | (cur3.y & km3.y)                        \
            | (cur4.x & km4.x) | (cur4.y & km4.y)                        \
            | (cur5.x & km5.x) | (cur5.y & km5.y)                        \
            | (cur6.x & km6.x) | (cur6.y & km6.y)                        \
            | (cur7.x & km7.x) | (cur7.y & km7.y)                        \
            | (cur8.x & km8.x) | (cur8.y & km8.y)                        \
            | (cur9.x & km9.x) | (cur9.y & km9.y)                        \
            | (cur10.x & km10.x) | (cur10.y & km10.y)                    \
            | (cur11.x & km11.x) | (cur11.y & km11.y);                   \
    u64 a_ = __ballot(sA_ == 0ull);                                      \
    u64 supw_ = 0ull, keepm_ = 0ull;                                     \
    while (a_) {                                                         \
      int k_ = __ffsll((unsigned long long)a_) - 1;                      \
      a_ &= a_ - 1ull;                                                   \
      if (!((supw_ >> k_) & 1ull)) {                                     \
        keepm_ |= 1ull << k_;                                            \
        ++nk;                                                            \
        if (nk >= POST_NMS) break;                                       \
        supw_ |= readlane64(DW, k_);                                     \
      }                                                                  \
    }                                                                    \
    if (lane == 0) {                                                     \
      u64 km_ = keepm_;                                                  \
      int c2_ = nk - __popcll((unsigned long long)keepm_);               \
      while (km_) {                                                      \
        int k_ = __ffsll((unsigned long long)km_) - 1;                   \
        km_ &= km_ - 1ull;                                               \
        s_kept[c2_++] = (u32)((C) * 64 + k_);                            \
      }                                                                  \
    }                                                                    \
    KM |= keepm_;                                                        \
    done = (nk >= POST_NMS);                                             \
  }

  LOADCUR(0); PREF(1);
  DO_CHUNK( 0, cur0.x,  km0.x ); if (done) goto chain_done; ROLL; PREF(2);
  DO_CHUNK( 1, cur0.y,  km0.y ); if (done) goto chain_done; ROLL; PREF(3);
  DO_CHUNK( 2, cur1.x,  km1.x ); if (done) goto chain_done; ROLL; PREF(4);
  DO_CHUNK( 3, cur1.y,  km1.y ); if (done) goto chain_done; ROLL; PREF(5);
  DO_CHUNK( 4, cur2.x,  km2.x ); if (done) goto chain_done; ROLL; PREF(6);
  DO_CHUNK( 5, cur2.y,  km2.y ); if (done) goto chain_done; ROLL; PREF(7);
  DO_CHUNK( 6, cur3.x,  km3.x ); if (done) goto chain_done; ROLL; PREF(8);
  DO_CHUNK( 7, cur3.y,  km3.y ); if (done) goto chain_done; ROLL; PREF(9);
  DO_CHUNK( 8, cur4.x,  km4.x ); if (done) goto chain_done; ROLL; PREF(10);
  DO_CHUNK( 9, cur4.y,  km4.y ); if (done) goto chain_done; ROLL; PREF(11);
  DO_CHUNK(10, cur5.x,  km5.x ); if (done) goto chain_done; ROLL; PREF(12);
  DO_CHUNK(11, cur5.y,  km5.y ); if (done) goto chain_done; ROLL; PREF(13);
  DO_CHUNK(12, cur6.x,  km6.x ); if (done) goto chain_done; ROLL; PREF(14);
  DO_CHUNK(13, cur6.y,  km6.y ); if (done) goto chain_done; ROLL; PREF(15);
  DO_CHUNK(14, cur7.x,  km7.x ); if (done) goto chain_done; ROLL; PREF(16);
  DO_CHUNK(15, cur7.y,  km7.y ); if (done) goto chain_done; ROLL; PREF(17);
  DO_CHUNK(16, cur8.x,  km8.x ); if (done) goto chain_done; ROLL; PREF(18);
  DO_CHUNK(17, cur8.y,  km8.y ); if (done) goto chain_done; ROLL; PREF(19);
  DO_CHUNK(18, cur9.x,  km9.x ); if (done) goto chain_done; ROLL; PREF(20);
  DO_CHUNK(19, cur9.y,  km9.y ); if (done) goto chain_done; ROLL; PREF(21);
  DO_CHUNK(20, cur10.x, km10.x); if (done) goto chain_done; ROLL; PREF(22);
  DO_CHUNK(21, cur10.y, km10.y); if (done) goto chain_done; ROLL; PREF(23);
  DO_CHUNK(22, cur11.x, km11.x); if (done) goto chain_done; ROLL;
  DO_CHUNK(23, cur11.y, km11.y);
chain_done: ;
#undef DO_CHUNK
#undef ROLL
#undef PREF
#undef LOADCUR

  // ---- phase C: exact fallback past candidate NCAND (not taken on this
  // data; correctness net). Round-1-verified register-NMS logic. ----
  if (nk < POST_NMS) {
    float4 kb[5];
    float  ka[5];
    #pragma unroll
    for (int s = 0; s < 5; ++s) {
      int t = s * 64 + lane;
      float4 v = make_float4(0.f, 0.f, 0.f, 0.f);
      if (t < nk) v = boxes_ws[b * PRE_NMS + s_kept[t]];
      kb[s] = v;
      ka[s] = (v.z - v.x) * (v.w - v.y);
    }
    for (int i = NCAND; i < PRE_NMS; ++i) {
      if (nk >= POST_NMS) break;
      float4 c = boxes_ws[b * PRE_NMS + i];
      float carea = (c.z - c.x) * (c.w - c.y);
      bool over = false;
      #pragma unroll
      for (int s = 0; s < 5; ++s) {
        if (s * 64 < nk) {
          if (s * 64 + lane < nk) {
            float iw = fminf(kb[s].z, c.z) - fmaxf(kb[s].x, c.x);
            float ih = fminf(kb[s].w, c.w) - fmaxf(kb[s].y, c.y);
            iw = fmaxf(iw, 0.0f);
            ih = fmaxf(ih, 0.0f);
            float inter = iw * ih;
            float uni = ka[s] + carea - inter;
            over = over || (inter > 0.7f * fmaxf(uni, 1e-8f));
          }
        }
      }
      if (__ballot((int)over) == 0ull) {
        int s = nk >> 6, l = nk & 63;
        #pragma unroll
        for (int q = 0; q < 5; ++q)
          if (q == s && lane == l) { kb[q] = c; ka[q] = carea; }
        if (lane == 0) s_kept[nk] = (u32)i;
        ++nk;
      }
    }
  }

  // ---- emit: first nk kept (score order), zero-pad to 300 ----
  float4* outv = (float4*)out;
  for (int t = lane; t < POST_NMS; t += 64) {
    float4 v = make_float4(0.f, 0.f, 0.f, 0.f);
    if (t < nk) v = boxes_ws[b * PRE_NMS + s_kept[t]];
    outv[b * POST_NMS + t] = v;
  }
}

// ---------------------------------------------------------------------------
// Fallback: round-1 monolithic kernel (verified) if ws is too small.
// ---------------------------------------------------------------------------
__global__ void __launch_bounds__(NTH)
rpn_proposal_mono(const float* __restrict__ scores,
                  const float* __restrict__ deltas,
                  float* __restrict__ out)
{
  __shared__ __align__(16) char smem[16384 + 32768 + 4096];
  u32* s_hist = (u32*)smem;
  u64* s_cand = (u64*)(smem + 16384);
  u32* s_sfx  = (u32*)(smem + 16384 + 32768);
  float4* s_box = (float4*)smem;
  __shared__ u32 s_kept[POST_NMS];
  __shared__ u32 s_meta[4];

  const int tid = threadIdx.x;
  const int b   = blockIdx.x;
  const float* sc = scores + b * NBOX;

  for (int t = tid; t < NBUCKET; t += NTH) s_hist[t] = 0;
  if (tid < 4) s_meta[tid] = 0;
  __syncthreads();
  for (int m = 0; m < PER; ++m) {
    int i = tid + m * NTH;
    if (i < NBOX) {
      float s = sc[i];
      int bk = (int)(s * (float)NBUCKET);
      bk = bk < 0 ? 0 : (bk > NBUCKET - 1 ? NBUCKET - 1 : bk);
      atomicAdd(&s_hist[bk], 1u);
    }
  }
  __syncthreads();
  {
    u32 g = s_hist[4*tid] + s_hist[4*tid+1] + s_hist[4*tid+2] + s_hist[4*tid+3];
    s_sfx[tid] = g;
  }
  __syncthreads();
  for (int d = 1; d < NTH; d <<= 1) {
    u32 v = (tid + d < NTH) ? s_sfx[tid + d] : 0u;
    __syncthreads();
    s_sfx[tid] += v;
    __syncthreads();
  }
  {
    u32 sg  = s_sfx[tid];
    u32 sgn = (tid < NTH - 1) ? s_sfx[tid + 1] : 0u;
    if (sg >= PRE_NMS && sgn < PRE_NMS) {
      u32 c = sgn;
      for (int t = 4 * tid + 3; t >= 4 * tid; --t) {
        c += s_hist[t];
        if (c >= PRE_NMS) { s_meta[0] = (u32)t; s_meta[1] = c; break; }
      }
    }
  }
  __syncthreads();
  const u32 T = s_meta[0];
  for (int m = 0; m < PER; ++m) {
    int i = tid + m * NTH;
    if (i < NBOX) {
      float s = sc[i];
      int bk = (int)(s * (float)NBUCKET);
      bk = bk < 0 ? 0 : (bk > NBUCKET - 1 ? NBUCKET - 1 : bk);
      if ((u32)bk >= T) {
        u32 pos = atomicAdd(&s_meta[2], 1u);
        if (pos < SEGCAP) {
          u64 key = ((u64)__float_as_uint(s) << 32) | (u32)(~(u32)i);
          s_cand[pos] = key;
        }
      }
    }
  }
  __syncthreads();
  {
    u32 C = s_meta[2]; if (C > SEGCAP) C = SEGCAP;
    for (u32 p = C + tid; p < SEGCAP; p += NTH) s_cand[p] = 0ull;
  }
  for (int kk = 2; kk <= SEGCAP; kk <<= 1) {
    for (int j = kk >> 1; j > 0; j >>= 1) {
      __syncthreads();
      #pragma unroll
      for (int m = 0; m < 2; ++m) {
        int t = tid + m * NTH;
        int i = ((t & ~(j - 1)) << 1) | (t & (j - 1));
        int p = i | j;
        u64 a  = s_cand[i];
        u64 bb = s_cand[p];
        bool desc = (i & kk) == 0;
        bool sw = desc ? (a < bb) : (a > bb);
        if (sw) { s_cand[i] = bb; s_cand[p] = a; }
      }
    }
  }
  __syncthreads();
  const float* dl = deltas + b * (4 * NA * HW);
  float4 bx[3];
  #pragma unroll
  for (int m = 0; m < 3; ++m) {
    int k = tid + m * NTH;
    if (k < PRE_NMS) {
      u64 key = s_cand[k];
      bx[m] = decode_box(dl, (int)(~(u32)key));
    }
  }
  __syncthreads();
  #pragma unroll
  for (int m = 0; m < 3; ++m) {
    int k = tid + m * NTH;
    if (k < PRE_NMS) s_box[k] = bx[m];
  }
  __syncthreads();
  if (tid < 64) {
    const int lane = tid;
    float4 kb[5];
    float  ka[5];
    int nk = 0;
    for (int i = 0; i < PRE_NMS; ++i) {
      if (nk >= POST_NMS) break;
      float4 c = s_box[i];
      float carea = (c.z - c.x) * (c.w - c.y);
      bool over = false;
      #pragma unroll
      for (int s = 0; s < 5; ++s) {
        if (s * 64 < nk) {
          if (s * 64 + lane < nk) {
            float iw = fminf(kb[s].z, c.z) - fmaxf(kb[s].x, c.x);
            float ih = fminf(kb[s].w, c.w) - fmaxf(kb[s].y, c.y);
            iw = fmaxf(iw, 0.0f);
            ih = fmaxf(ih, 0.0f);
            float inter = iw * ih;
            float uni = ka[s] + carea - inter;
            over = over || (inter > 0.7f * fmaxf(uni, 1e-8f));
          }
        }
      }
      if (__ballot((int)over) == 0ull) {
        int s = nk >> 6, l = nk & 63;
        #pragma unroll
        for (int q = 0; q < 5; ++q)
          if (q == s && lane == l) { kb[q] = c; ka[q] = carea; }
        if (lane == 0) s_kept[nk] = (u32)i;
        ++nk;
      }
    }
    if (lane == 0) s_meta[3] = (u32)nk;
  }
  __syncthreads();
  if (tid < POST_NMS) {
    u32 nk = s_meta[3];
    float4 v = make_float4(0.0f, 0.0f, 0.0f, 0.0f);
    if ((u32)tid < nk) v = s_box[s_kept[tid]];
    ((float4*)out)[b * POST_NMS + tid] = v;
  }
}

extern "C" void kernel_launch(void* const* d_in, const int* in_sizes, int n_in,
                              void* d_out, int out_size, void* d_ws, size_t ws_size,
                              hipStream_t stream) {
  const float* scores = (const float*)d_in[0];
  const float* deltas = (const float*)d_in[1];
  (void)in_sizes; (void)n_in; (void)out_size;

  const size_t mask_off   = 196608;                                  // 192KB aligned
  const size_t mask_bytes = (size_t)NB * NCAND * MW * sizeof(u64);   // 1.18 MB
  const size_t need       = mask_off + mask_bytes;

  if (ws_size >= need) {
    float4* boxes_ws = (float4*)d_ws;
    u64*    masks2   = (u64*)((char*)d_ws + mask_off);
    topk_rank_decode_kernel<<<dim3(NB), dim3(NTH), 0, stream>>>(scores, deltas, boxes_ws);
    mask_corner_kernel<<<dim3(MW, NCAND / 256, NB), dim3(256), 0, stream>>>(boxes_ws, masks2);
    nms_reduce_kernel<<<dim3(NB), dim3(64), 0, stream>>>(boxes_ws, masks2, (float*)d_out);
  } else {
    rpn_proposal_mono<<<dim3(NB), dim3(NTH), 0, stream>>>(scores, deltas, (float*)d_out);
  }
}